// Round 1
// baseline (1310.278 us; speedup 1.0000x reference)
//
#include <hip/hip_runtime.h>
#include <hip/hip_bf16.h>

// Problem: StyleGAN2-style modulated conv. B=16, C=128 (o==i), H=W=128, K=3.
// out[b,o,y,x] = sum_{i,ky,kx} wmod[b,o,i,ky,kx] * xpad[b,i,y+ky-1,x+kx-1]
// wmod = w * (1/sqrt(1152)/wmax[o]) * sn[b,i] * coe[b,o]
//   sn[b,i]  = style[b,i] / max_i |style[b,i]|
//   coe[b,o] = rsqrt( sum_{i,k}(w*scale*sn)^2 + 1e-8 )

#define BATCH 16
#define CH    128
#define HW    128
#define KK9   9
#define WPITCH 1152   // CH*KK9
#define TI    8       // input-channel chunk

// ws layout (floats):
//   [0,128)            wmax[o]
//   [128, 2176)        sn[b*128+i]
//   [2176, 4224)       Afac[b*128+o]  (= scale * coe)
//   [4224, 4224+147456) w_t[(i*9+kk)*128 + o]   (transposed weight)
#define WS_WMAX 0
#define WS_SN   128
#define WS_AFAC 2176
#define WS_WT   4224

// ---------------------------------------------------------------- k0: transpose
__global__ __launch_bounds__(256) void k0_transpose(const float* __restrict__ w,
                                                    float* __restrict__ ws) {
    int idx = blockIdx.x * 256 + threadIdx.x;   // [0, 147456)
    if (idx < CH * WPITCH) {
        int kt = idx >> 7;        // i*9+kk, [0,1152)
        int o  = idx & 127;
        ws[WS_WT + idx] = w[(size_t)o * WPITCH + kt];
    }
}

// ---------------------------------------------------------------- k1: norms
__global__ __launch_bounds__(256) void k1_norms(const float* __restrict__ style,
                                                const float* __restrict__ weight,
                                                float* __restrict__ ws) {
    __shared__ float red[4];
    const int bid = blockIdx.x;
    const int t = threadIdx.x;
    if (bid < 128) {
        // wmax[o] over 1152 elements
        const int o = bid;
        float m = 0.f;
        for (int idx = t; idx < WPITCH; idx += 256)
            m = fmaxf(m, fabsf(weight[(size_t)o * WPITCH + idx]));
        #pragma unroll
        for (int off = 32; off > 0; off >>= 1)
            m = fmaxf(m, __shfl_down(m, off, 64));
        if ((t & 63) == 0) red[t >> 6] = m;
        __syncthreads();
        if (t == 0)
            ws[WS_WMAX + o] = fmaxf(fmaxf(red[0], red[1]), fmaxf(red[2], red[3]));
    } else {
        // sn[b][i] = style / ||style||_inf
        const int b = bid - 128;
        float v = (t < CH) ? style[b * CH + t] : 0.f;
        float m = fabsf(v);
        #pragma unroll
        for (int off = 32; off > 0; off >>= 1)
            m = fmaxf(m, __shfl_down(m, off, 64));
        if ((t & 63) == 0) red[t >> 6] = m;
        __syncthreads();
        float smax = fmaxf(fmaxf(red[0], red[1]), fmaxf(red[2], red[3]));
        if (t < CH) ws[WS_SN + b * CH + t] = v / smax;
    }
}

// ---------------------------------------------------------------- k2: demod coe
__global__ __launch_bounds__(256) void k2_coe(const float* __restrict__ weight,
                                              float* __restrict__ ws) {
    const int o = blockIdx.x;
    const int b = blockIdx.y;
    const int t = threadIdx.x;
    const float* sn = ws + WS_SN + b * CH;
    float s = 0.f;
    for (int idx = t; idx < WPITCH; idx += 256) {
        int i = idx / 9;
        float v = weight[(size_t)o * WPITCH + idx] * sn[i];
        s += v * v;
    }
    #pragma unroll
    for (int off = 32; off > 0; off >>= 1) s += __shfl_down(s, off, 64);
    __shared__ float red[4];
    if ((t & 63) == 0) red[t >> 6] = s;
    __syncthreads();
    if (t == 0) {
        float S = red[0] + red[1] + red[2] + red[3];
        float wm = ws[WS_WMAX + o];
        float scale = 1.0f / (sqrtf(1152.0f) * wm);
        float coe = rsqrtf(scale * scale * S + 1e-8f);
        ws[WS_AFAC + b * CH + o] = scale * coe;
    }
}

// ---------------------------------------------------------------- k3: conv
// One block per (h, b). Tile: 128 o x 128 px (one output row). 256 threads,
// each computes 8 o x 8 px. TI=8 input channels per chunk, 16 chunks.
#define XPITCH 132   // padded row stride for x tile (16B-aligned b128 reads)

__global__ __launch_bounds__(256) void k3_conv(const float* __restrict__ x,
                                               const float* __restrict__ ws,
                                               float* __restrict__ out) {
    const int h = blockIdx.x;
    const int b = blockIdx.y;
    const int t = threadIdx.x;
    const int og = t >> 4;   // 0..15 -> o = og*8 + j
    const int pg = t & 15;   // 0..15 -> px = pg*8 + p

    __shared__ float x_lds[TI * 3 * XPITCH];     // [ti][r(3)][c(132)]
    __shared__ float w_lds[TI * 9 * 128];        // [(ti*9+kk)*128 + o]
    __shared__ float Af_l[128];
    __shared__ float sn_l[128];

    if (t < 128) {
        Af_l[t] = ws[WS_AFAC + b * CH + t];
        sn_l[t] = ws[WS_SN + b * CH + t];
    }

    float acc[8][8];
    #pragma unroll
    for (int j = 0; j < 8; ++j)
        #pragma unroll
        for (int p = 0; p < 8; ++p) acc[j][p] = 0.f;

    const float4* wt4 = (const float4*)(ws + WS_WT);
    float4* w_lds4 = (float4*)w_lds;
    const float4* Af4 = (const float4*)Af_l;

    #pragma unroll 1
    for (int ci = 0; ci < CH / TI; ++ci) {
        const int ib = ci * TI;
        __syncthreads();   // protect LDS from prev iter's readers (also covers Af_l/sn_l first time)

        // --- stage x: TI channels x 3 rows x 130 cols (zero-padded halo)
        for (int idx = t; idx < TI * 3 * 130; idx += 256) {
            int ti  = idx / 390;
            int rem = idx - ti * 390;
            int r   = rem / 130;
            int c   = rem - r * 130;
            int row = h + r - 1;
            int col = c - 1;
            float v = 0.f;
            if ((unsigned)row < 128u && (unsigned)col < 128u)
                v = x[(((size_t)b * CH + ib + ti) * HW + row) * HW + col];
            x_lds[(ti * 3 + r) * XPITCH + c] = v;
        }

        // --- stage w (transposed layout: contiguous in global AND in LDS),
        //     applying modulation factors on the fly.
        for (int idx = t; idx < TI * 9 * 32; idx += 256) {   // float4 units
            int kt = idx >> 5;        // 0..71 = ti*9+kk
            int o4 = idx & 31;
            int ti = kt / 9;
            float4 wv = wt4[(size_t)ib * 9 * 32 + idx];
            float4 af = Af4[o4];
            float  s  = sn_l[ib + ti];
            float4 r;
            r.x = wv.x * af.x * s;
            r.y = wv.y * af.y * s;
            r.z = wv.z * af.z * s;
            r.w = wv.w * af.w * s;
            w_lds4[idx] = r;
        }
        __syncthreads();

        // --- compute
        #pragma unroll 1
        for (int ti = 0; ti < TI; ++ti) {
            float xv[3][12];
            #pragma unroll
            for (int ky = 0; ky < 3; ++ky) {
                #pragma unroll
                for (int q = 0; q < 3; ++q) {
                    float4 v = *(const float4*)&x_lds[(ti * 3 + ky) * XPITCH + pg * 8 + q * 4];
                    xv[ky][q * 4 + 0] = v.x;
                    xv[ky][q * 4 + 1] = v.y;
                    xv[ky][q * 4 + 2] = v.z;
                    xv[ky][q * 4 + 3] = v.w;
                }
            }
            #pragma unroll
            for (int kk = 0; kk < 9; ++kk) {
                const int ky = kk / 3;
                const int kx = kk % 3;
                float wv[8];
                #pragma unroll
                for (int q = 0; q < 2; ++q) {
                    float4 v = *(const float4*)&w_lds[(ti * 9 + kk) * 128 + og * 8 + q * 4];
                    wv[q * 4 + 0] = v.x;
                    wv[q * 4 + 1] = v.y;
                    wv[q * 4 + 2] = v.z;
                    wv[q * 4 + 3] = v.w;
                }
                #pragma unroll
                for (int j = 0; j < 8; ++j)
                    #pragma unroll
                    for (int p = 0; p < 8; ++p)
                        acc[j][p] = fmaf(wv[j], xv[ky][p + kx], acc[j][p]);
            }
        }
    }

    // --- epilogue: coalesced float4 stores
    const size_t obase = ((size_t)b * CH) * (HW * HW) + (size_t)h * HW;
    #pragma unroll
    for (int j = 0; j < 8; ++j) {
        int o = og * 8 + j;
        float4 v0 = {acc[j][0], acc[j][1], acc[j][2], acc[j][3]};
        float4 v1 = {acc[j][4], acc[j][5], acc[j][6], acc[j][7]};
        *(float4*)&out[obase + (size_t)o * (HW * HW) + pg * 8]     = v0;
        *(float4*)&out[obase + (size_t)o * (HW * HW) + pg * 8 + 4] = v1;
    }
}

// ---------------------------------------------------------------- launch
extern "C" void kernel_launch(void* const* d_in, const int* in_sizes, int n_in,
                              void* d_out, int out_size, void* d_ws, size_t ws_size,
                              hipStream_t stream) {
    const float* x      = (const float*)d_in[0];
    const float* style  = (const float*)d_in[1];
    const float* weight = (const float*)d_in[2];
    float* out = (float*)d_out;
    float* ws  = (float*)d_ws;

    k0_transpose<<<(CH * WPITCH + 255) / 256, 256, 0, stream>>>(weight, ws);
    k1_norms<<<144, 256, 0, stream>>>(style, weight, ws);
    k2_coe<<<dim3(CH, BATCH), 256, 0, stream>>>(weight, ws);
    k3_conv<<<dim3(HW, BATCH), 256, 0, stream>>>(x, ws, out);
}

// Round 2
// 315.017 us; speedup vs baseline: 4.1594x; 4.1594x over previous
//
#include <hip/hip_runtime.h>
#include <hip/hip_bf16.h>

// StyleGAN2-style modulated conv. B=16, C=128 (o==i), H=W=128, K=3.
// out[b,o,y,x] = sum_{i,ky,kx} wmod[b,o,i,ky,kx] * xpad[b,i,y+ky-1,x+kx-1]
// wmod = w * (1/sqrt(1152)/wmax[o]) * sn[b,i] * coe[b,o]
//
// R2: bf16 MFMA implicit GEMM (9 shifted K=128 GEMMs), weights pre-swizzled
// to A-fragment-linear bf16 in ws; x transposed to [row][col][i] in LDS.

#define BATCH 16
#define CH    128
#define HW    128
#define WPITCH 1152   // CH*9

// ws layout:
//   floats: [0,128) wmax | [128,2176) sn | [2176,4224) Afac | [4224,+147456) w_t[(i*9+kk)*128+o]
//   bytes 606720...: wfrag bf16, [b][kk][ci(4)][mo(8)][lane(64)][j(8)]
#define WS_WMAX 0
#define WS_SN   128
#define WS_AFAC 2176
#define WS_WT   4224
#define WFRAG_BYTE_OFF 606720
#define WFRAG_BYTES    4718592
#define WS_NEEDED      (WFRAG_BYTE_OFF + WFRAG_BYTES)

typedef short  s8v  __attribute__((ext_vector_type(8)));
typedef float  f4v  __attribute__((ext_vector_type(4)));

__device__ inline unsigned short f2bf(float f) {
    union { float f; unsigned int u; } v; v.f = f;
    unsigned int r = v.u + 0x7FFFu + ((v.u >> 16) & 1u);   // RNE
    return (unsigned short)(r >> 16);
}

// ---------------------------------------------------------------- k0: transpose w -> wt[kt][o]
__global__ __launch_bounds__(256) void k0_transpose(const float* __restrict__ w,
                                                    float* __restrict__ ws) {
    int idx = blockIdx.x * 256 + threadIdx.x;
    if (idx < CH * WPITCH) {
        int kt = idx >> 7;
        int o  = idx & 127;
        ws[WS_WT + idx] = w[(size_t)o * WPITCH + kt];
    }
}

// ---------------------------------------------------------------- k1: norms
__global__ __launch_bounds__(256) void k1_norms(const float* __restrict__ style,
                                                const float* __restrict__ weight,
                                                float* __restrict__ ws) {
    __shared__ float red[4];
    const int bid = blockIdx.x;
    const int t = threadIdx.x;
    if (bid < 128) {
        const int o = bid;
        float m = 0.f;
        for (int idx = t; idx < WPITCH; idx += 256)
            m = fmaxf(m, fabsf(weight[(size_t)o * WPITCH + idx]));
        #pragma unroll
        for (int off = 32; off > 0; off >>= 1)
            m = fmaxf(m, __shfl_down(m, off, 64));
        if ((t & 63) == 0) red[t >> 6] = m;
        __syncthreads();
        if (t == 0)
            ws[WS_WMAX + o] = fmaxf(fmaxf(red[0], red[1]), fmaxf(red[2], red[3]));
    } else {
        const int b = bid - 128;
        float v = (t < CH) ? style[b * CH + t] : 0.f;
        float m = fabsf(v);
        #pragma unroll
        for (int off = 32; off > 0; off >>= 1)
            m = fmaxf(m, __shfl_down(m, off, 64));
        if ((t & 63) == 0) red[t >> 6] = m;
        __syncthreads();
        float smax = fmaxf(fmaxf(red[0], red[1]), fmaxf(red[2], red[3]));
        if (t < CH) ws[WS_SN + b * CH + t] = v / smax;
    }
}

// ---------------------------------------------------------------- k2: demod coe -> Afac
__global__ __launch_bounds__(256) void k2_coe(const float* __restrict__ weight,
                                              float* __restrict__ ws) {
    const int o = blockIdx.x;
    const int b = blockIdx.y;
    const int t = threadIdx.x;
    const float* sn = ws + WS_SN + b * CH;
    float s = 0.f;
    for (int idx = t; idx < WPITCH; idx += 256) {
        int i = idx / 9;
        float v = weight[(size_t)o * WPITCH + idx] * sn[i];
        s += v * v;
    }
    #pragma unroll
    for (int off = 32; off > 0; off >>= 1) s += __shfl_down(s, off, 64);
    __shared__ float red[4];
    if ((t & 63) == 0) red[t >> 6] = s;
    __syncthreads();
    if (t == 0) {
        float S = red[0] + red[1] + red[2] + red[3];
        float wm = ws[WS_WMAX + o];
        float scale = 1.0f / (sqrtf(1152.0f) * wm);
        float coe = rsqrtf(scale * scale * S + 1e-8f);
        ws[WS_AFAC + b * CH + o] = scale * coe;
    }
}

// ---------------------------------------------------------------- k3: swizzle wmod -> A-frag-linear bf16
// frag element: lane holds A[m=o=mo*16+(lane&15)][k=i=ci*32+(lane>>4)*8+j], j=0..7
__global__ __launch_bounds__(256) void k3_swz(const float* __restrict__ ws,
                                              unsigned short* __restrict__ wfrag) {
    int t = blockIdx.x * 256 + threadIdx.x;      // [0, 294912)
    const int lane = t & 63;
    int f = t >> 6;                               // [0, 4608)
    const int mo = f & 7;  f >>= 3;
    const int ci = f & 3;  f >>= 2;
    const int kk = f % 9;
    const int b  = f / 9;
    const int o  = mo * 16 + (lane & 15);
    const int i0 = ci * 32 + (lane >> 4) * 8;
    const float af = ws[WS_AFAC + b * CH + o];
    union { unsigned short u[8]; uint4 v; } pk;
    #pragma unroll
    for (int j = 0; j < 8; ++j) {
        int i = i0 + j;
        float v = ws[WS_WT + (size_t)(i * 9 + kk) * 128 + o] * af * ws[WS_SN + b * CH + i];
        pk.u[j] = f2bf(v);
    }
    *(uint4*)(wfrag + (size_t)t * 8) = pk.v;
}

// ---------------------------------------------------------------- k4: MFMA conv
// Block: (h-pair, b). 256 thr = 4 waves. Tile 128 o x 256 px (rows h0, h0+1).
// Wave w: o-half = w&1 (64 o), output row = h0 + (w>>1) (128 px).
// K-loop: 4 chunks of 32 input channels; per chunk 9 kernel taps.
#define XROW 132   // allocated cols (used 0..129)
#define XIP  40    // i-pitch (pad 32 -> 40: 80B stride, 2-way-conflict-free, 16B aligned)

__global__ __launch_bounds__(256, 2) void k4_mfma(const float* __restrict__ x,
                                                  const unsigned short* __restrict__ wfrag,
                                                  float* __restrict__ out) {
    const int h0 = blockIdx.x * 2;
    const int b  = blockIdx.y;
    const int t  = threadIdx.x;
    const int lane = t & 63;
    const int w    = t >> 6;
    const int ohalf = w & 1;
    const int rsel  = w >> 1;
    const int ln15  = lane & 15;
    const int quad  = lane >> 4;

    __shared__ unsigned short xT[4 * XROW * XIP];   // [r(4)][c(132)][i(40)]

    f4v acc[4][8];
    #pragma unroll
    for (int mt = 0; mt < 4; ++mt)
        #pragma unroll
        for (int nt = 0; nt < 8; ++nt)
            acc[mt][nt] = (f4v){0.f, 0.f, 0.f, 0.f};

    #pragma unroll 1
    for (int ci = 0; ci < 4; ++ci) {
        const int ib = ci * 32;
        __syncthreads();

        // --- stage x chunk: 4 rows x 130 cols x 32 i, transposed to [r][c][i] bf16.
        // Each thread gathers 8 channels (coalesced global reads), one ds_write_b128.
        #pragma unroll 1
        for (int idx = t; idx < 16 * 130; idx += 256) {
            int c  = idx % 130;
            int ri = idx / 130;          // 0..15
            int r   = ri & 3;
            int ibk = ri >> 2;
            int row = h0 - 1 + r;
            int col = c - 1;
            union { unsigned short u[8]; s8v v; } pk;
            if ((unsigned)row < 128u && (unsigned)col < 128u) {
                const float* xp = x + (((size_t)(b * CH + ib + ibk * 8)) * HW + row) * HW + col;
                #pragma unroll
                for (int j = 0; j < 8; ++j)
                    pk.u[j] = f2bf(xp[(size_t)j * HW * HW]);
            } else {
                #pragma unroll
                for (int j = 0; j < 8; ++j) pk.u[j] = 0;
            }
            *(s8v*)&xT[(r * XROW + c) * XIP + ibk * 8] = pk.v;
        }
        __syncthreads();

        // --- 9 taps
        #pragma unroll 1
        for (int ky = 0; ky < 3; ++ky) {
            const int r = rsel + ky;
            #pragma unroll 1
            for (int kx = 0; kx < 3; ++kx) {
                const int kk = ky * 3 + kx;
                // A-frags direct from global (frag-linear, coalesced 16B/lane)
                s8v a[4];
                #pragma unroll
                for (int mt = 0; mt < 4; ++mt) {
                    int mo = ohalf * 4 + mt;
                    size_t off = ((size_t)(((b * 9 + kk) * 4 + ci) * 8 + mo) * 64 + lane) * 8;
                    a[mt] = *(const s8v*)(wfrag + off);
                }
                // B-frags from LDS
                s8v bf[8];
                #pragma unroll
                for (int nt = 0; nt < 8; ++nt) {
                    int c = nt * 16 + ln15 + kx;
                    bf[nt] = *(const s8v*)&xT[(r * XROW + c) * XIP + quad * 8];
                }
                #pragma unroll
                for (int mt = 0; mt < 4; ++mt)
                    #pragma unroll
                    for (int nt = 0; nt < 8; ++nt)
                        acc[mt][nt] = __builtin_amdgcn_mfma_f32_16x16x32_bf16(
                            a[mt], bf[nt], acc[mt][nt], 0, 0, 0);
            }
        }
    }

    // --- epilogue: C/D layout col(n=px)=lane&15, row(m=o)=quad*4+reg
    const int orow = h0 + rsel;
    #pragma unroll
    for (int mt = 0; mt < 4; ++mt) {
        int o = ohalf * 64 + mt * 16 + quad * 4;
        #pragma unroll
        for (int nt = 0; nt < 8; ++nt) {
            int xcol = nt * 16 + ln15;
            float* op = out + (((size_t)(b * CH + o)) * HW + orow) * HW + xcol;
            #pragma unroll
            for (int reg = 0; reg < 4; ++reg)
                op[(size_t)reg * HW * HW] = acc[mt][nt][reg];
        }
    }
}

// ---------------------------------------------------------------- fallback fp32 conv (R1)
#define TI    8
#define XPITCH 132
__global__ __launch_bounds__(256) void k3_conv(const float* __restrict__ x,
                                               const float* __restrict__ ws,
                                               float* __restrict__ out) {
    const int h = blockIdx.x;
    const int b = blockIdx.y;
    const int t = threadIdx.x;
    const int og = t >> 4;
    const int pg = t & 15;

    __shared__ float x_lds[TI * 3 * XPITCH];
    __shared__ float w_lds[TI * 9 * 128];
    __shared__ float Af_l[128];
    __shared__ float sn_l[128];

    if (t < 128) {
        Af_l[t] = ws[WS_AFAC + b * CH + t];
        sn_l[t] = ws[WS_SN + b * CH + t];
    }
    float acc[8][8];
    #pragma unroll
    for (int j = 0; j < 8; ++j)
        #pragma unroll
        for (int p = 0; p < 8; ++p) acc[j][p] = 0.f;

    const float4* wt4 = (const float4*)(ws + WS_WT);
    float4* w_lds4 = (float4*)w_lds;
    const float4* Af4 = (const float4*)Af_l;

    #pragma unroll 1
    for (int ci = 0; ci < CH / TI; ++ci) {
        const int ib = ci * TI;
        __syncthreads();
        for (int idx = t; idx < TI * 3 * 130; idx += 256) {
            int ti  = idx / 390;
            int rem = idx - ti * 390;
            int r   = rem / 130;
            int c   = rem - r * 130;
            int row = h + r - 1;
            int col = c - 1;
            float v = 0.f;
            if ((unsigned)row < 128u && (unsigned)col < 128u)
                v = x[(((size_t)b * CH + ib + ti) * HW + row) * HW + col];
            x_lds[(ti * 3 + r) * XPITCH + c] = v;
        }
        for (int idx = t; idx < TI * 9 * 32; idx += 256) {
            int kt = idx >> 5;
            int o4 = idx & 31;
            int ti = kt / 9;
            float4 wv = wt4[(size_t)ib * 9 * 32 + idx];
            float4 af = Af4[o4];
            float  s  = sn_l[ib + ti];
            float4 rr;
            rr.x = wv.x * af.x * s; rr.y = wv.y * af.y * s;
            rr.z = wv.z * af.z * s; rr.w = wv.w * af.w * s;
            w_lds4[idx] = rr;
        }
        __syncthreads();
        #pragma unroll 1
        for (int ti = 0; ti < TI; ++ti) {
            float xv[3][12];
            #pragma unroll
            for (int ky = 0; ky < 3; ++ky)
                #pragma unroll
                for (int q = 0; q < 3; ++q) {
                    float4 v = *(const float4*)&x_lds[(ti * 3 + ky) * XPITCH + pg * 8 + q * 4];
                    xv[ky][q*4+0] = v.x; xv[ky][q*4+1] = v.y;
                    xv[ky][q*4+2] = v.z; xv[ky][q*4+3] = v.w;
                }
            #pragma unroll
            for (int kk = 0; kk < 9; ++kk) {
                const int ky = kk / 3;
                const int kx = kk % 3;
                float wv[8];
                #pragma unroll
                for (int q = 0; q < 2; ++q) {
                    float4 v = *(const float4*)&w_lds[(ti * 9 + kk) * 128 + og * 8 + q * 4];
                    wv[q*4+0] = v.x; wv[q*4+1] = v.y; wv[q*4+2] = v.z; wv[q*4+3] = v.w;
                }
                #pragma unroll
                for (int j = 0; j < 8; ++j)
                    #pragma unroll
                    for (int p = 0; p < 8; ++p)
                        acc[j][p] = fmaf(wv[j], xv[ky][p + kx], acc[j][p]);
            }
        }
    }
    const size_t obase = ((size_t)b * CH) * (HW * HW) + (size_t)h * HW;
    #pragma unroll
    for (int j = 0; j < 8; ++j) {
        int o = og * 8 + j;
        float4 v0 = {acc[j][0], acc[j][1], acc[j][2], acc[j][3]};
        float4 v1 = {acc[j][4], acc[j][5], acc[j][6], acc[j][7]};
        *(float4*)&out[obase + (size_t)o * (HW * HW) + pg * 8]     = v0;
        *(float4*)&out[obase + (size_t)o * (HW * HW) + pg * 8 + 4] = v1;
    }
}

// ---------------------------------------------------------------- launch
extern "C" void kernel_launch(void* const* d_in, const int* in_sizes, int n_in,
                              void* d_out, int out_size, void* d_ws, size_t ws_size,
                              hipStream_t stream) {
    const float* x      = (const float*)d_in[0];
    const float* style  = (const float*)d_in[1];
    const float* weight = (const float*)d_in[2];
    float* out = (float*)d_out;
    float* ws  = (float*)d_ws;

    k0_transpose<<<(CH * WPITCH + 255) / 256, 256, 0, stream>>>(weight, ws);
    k1_norms<<<144, 256, 0, stream>>>(style, weight, ws);
    k2_coe<<<dim3(CH, BATCH), 256, 0, stream>>>(weight, ws);

    if (ws_size >= (size_t)WS_NEEDED) {
        unsigned short* wfrag = (unsigned short*)((char*)d_ws + WFRAG_BYTE_OFF);
        k3_swz<<<1152, 256, 0, stream>>>(ws, wfrag);
        k4_mfma<<<dim3(HW / 2, BATCH), 256, 0, stream>>>(x, wfrag, out);
    } else {
        k3_conv<<<dim3(HW, BATCH), 256, 0, stream>>>(x, ws, out);
    }
}